// Round 1
// baseline (389.575 us; speedup 1.0000x reference)
//
#include <hip/hip_runtime.h>
#include <hip/hip_bf16.h>
#include <math.h>

#define NPTS 65536
#define MRAY 16
#define NAPP 48
#define HIDN 128
#define PPB 4
#define BLOCK 512
#define GRID 2048

__device__ __forceinline__ float sigmoidf_(float x) { return 1.0f / (1.0f + __expf(-x)); }

// Classify ray_mask element dtype from the raw words.
// flag: 0 = 1-byte (uint8 bool), 1 = 4-byte word (int32 or float32; decode !=0), 2 = 8-byte (int64)
__global__ void detect_mask(const unsigned int* __restrict__ rm, int* __restrict__ flag) {
    bool bad = false, isf32 = false, odd_nz = false, even_one = false;
    for (int i = 0; i < 512; i++) {
        unsigned v = rm[i];
        if (v != 0u && v != 1u && v != 0x3F800000u) bad = true;
        if (v == 0x3F800000u) isf32 = true;
        if ((i & 1) && v != 0u) odd_nz = true;
        if (!(i & 1) && v != 0u) even_one = true;
    }
    int f;
    if (bad) f = 0;                       // packed bytes -> uint8
    else if (isf32) f = 1;                // float32 0.0/1.0 (word != 0 decode works)
    else if (!odd_nz && even_one) f = 2;  // int64 0/1
    else f = 1;                           // int32 0/1
    flag[0] = f;
}

struct PtScr {
    float din[56];        // [xyz(3), viewdir(3), app(48)]
    float nf[48];         // app + 0.01*noise
    float base[128];      // bounce-MLP layer1 const part
    float bas[12];        // basis columns: bas[i*3+0]=t_i, +1=b_i, +2=bN_i
    float misc[16];       // 0..2 = -viewdir (V), 3..5 diffuse, 6 r1, 7 a2, 8 scale
    float rayacc[16][4];  // per-ray contribution rgb + mask
    float wred[2][4];     // per-wave dense layer2 partials
};

__global__ __launch_bounds__(BLOCK) void rb_main(
    const float* __restrict__ xyzs, const float* __restrict__ app,
    const float* __restrict__ vdirs, const float* __restrict__ normals,
    const float* __restrict__ noise, const float* __restrict__ uu,
    const float* __restrict__ Wd1, const float* __restrict__ bd1,
    const float* __restrict__ Wd2, const float* __restrict__ bd2,
    const float* __restrict__ Wb1, const float* __restrict__ bb1,
    const float* __restrict__ Wb2, const float* __restrict__ bb2,
    const void* __restrict__ raym, const int* __restrict__ flagp,
    float* __restrict__ out)
{
    __shared__ float wb1s[64 * 128];
    __shared__ float bd1s[128], bb1s[128];
    __shared__ float wd2c[128 * 4];   // Wd2 columns 0,1,2,6
    __shared__ float bd2c[4];
    __shared__ float wb2s[128 * 3];
    __shared__ float bb2s[3];
    __shared__ PtScr scr[PPB];

    const int tid = threadIdx.x;

    for (int i = tid; i < 64 * 128; i += BLOCK) wb1s[i] = Wb1[i];
    for (int i = tid; i < 128; i += BLOCK) { bd1s[i] = bd1[i]; bb1s[i] = bb1[i]; }
    for (int i = tid; i < 128; i += BLOCK) {
        wd2c[i * 4 + 0] = Wd2[i * 9 + 0];
        wd2c[i * 4 + 1] = Wd2[i * 9 + 1];
        wd2c[i * 4 + 2] = Wd2[i * 9 + 2];
        wd2c[i * 4 + 3] = Wd2[i * 9 + 6];
    }
    for (int i = tid; i < 128 * 3; i += BLOCK) wb2s[i] = Wb2[i];
    if (tid == 0) {
        bd2c[0] = bd2[0]; bd2c[1] = bd2[1]; bd2c[2] = bd2[2]; bd2c[3] = bd2[6];
        bb2s[0] = bb2[0]; bb2s[1] = bb2[1]; bb2s[2] = bb2[2];
    }
    __syncthreads();

    const int flag = flagp[0];
    const int pg = tid >> 7;     // point group within block (0..3)
    const int t = tid & 127;     // thread within point group
    PtScr& S = scr[pg];

    for (int n = blockIdx.x * PPB + pg; n < NPTS; n += GRID * PPB) {
        __syncthreads();  // protect per-point LDS reuse across iterations

        // ---- phase 1: load per-point inputs ----
        if (t < 48) {
            float a = app[n * 48 + t];
            S.din[6 + t] = a;
            S.nf[t] = fmaf(0.01f, noise[n * 48 + t], a);
        } else if (t < 51) {
            int i = t - 48; S.din[i] = xyzs[n * 3 + i];
        } else if (t < 54) {
            int i = t - 51; float v = vdirs[n * 3 + i];
            S.din[3 + i] = v; S.misc[i] = -v;
        } else if (t == 54) {
            float nx = normals[n * 3 + 0], ny = normals[n * 3 + 1], nz = normals[n * 3 + 2];
            float inv = 1.0f / (sqrtf(nx * nx + ny * ny + nz * nz) + 1e-8f);
            float bx = nx * inv, by = ny * inv, bz = nz * inv;
            float ux, uy, uz;
            if (fabsf(bz) < 0.99f) { ux = 0.f; uy = 0.f; uz = 1.f; }
            else                   { ux = 1.f; uy = 0.f; uz = 0.f; }
            float tx = uy * bz - uz * by;
            float ty = uz * bx - ux * bz;
            float tz = ux * by - uy * bx;
            float tin = 1.0f / (sqrtf(tx * tx + ty * ty + tz * tz) + 1e-8f);
            tx *= tin; ty *= tin; tz *= tin;
            float ex = by * tz - bz * ty;
            float ey = bz * tx - bx * tz;
            float ez = bx * ty - by * tx;
            S.bas[0] = tx; S.bas[1] = ex; S.bas[2] = bx;
            S.bas[3] = ty; S.bas[4] = ey; S.bas[5] = by;
            S.bas[6] = tz; S.bas[7] = ez; S.bas[8] = bz;
        }
        __syncthreads();

        // ---- phase 2: dense MLP layer1 + bounce-MLP const part ----
        float hj = bd1s[t];
        #pragma unroll 9
        for (int k = 0; k < 54; k++) hj = fmaf(S.din[k], Wd1[k * 128 + t], hj);
        hj = fmaxf(hj, 0.0f);

        float basej = bb1s[t];
        #pragma unroll
        for (int k = 0; k < 3; k++) basej = fmaf(S.misc[k], wb1s[k * 128 + t], basej);            // eV rows 0..2
        #pragma unroll
        for (int k = 0; k < 3; k++) basej = fmaf(S.bas[k * 3 + 2], wb1s[(6 + k) * 128 + t], basej); // eN rows 6..8
        #pragma unroll 8
        for (int k = 0; k < 48; k++) basej = fmaf(S.nf[k], wb1s[(15 + k) * 128 + t], basej);      // efeat rows 15..62

        // dense layer2 partials (cols 0,1,2,6), wave reduce
        float p0 = hj * wd2c[t * 4 + 0];
        float p1 = hj * wd2c[t * 4 + 1];
        float p2 = hj * wd2c[t * 4 + 2];
        float p3 = hj * wd2c[t * 4 + 3];
        #pragma unroll
        for (int off = 32; off >= 1; off >>= 1) {
            p0 += __shfl_down(p0, off);
            p1 += __shfl_down(p1, off);
            p2 += __shfl_down(p2, off);
            p3 += __shfl_down(p3, off);
        }
        if ((tid & 63) == 0) {
            int w = (t >> 6) & 1;
            S.wred[w][0] = p0; S.wred[w][1] = p1; S.wred[w][2] = p2; S.wred[w][3] = p3;
        }
        __syncthreads();

        if (t == 0) {
            float d0 = S.wred[0][0] + S.wred[1][0] + bd2c[0];
            float d1 = S.wred[0][1] + S.wred[1][1] + bd2c[1];
            float d2 = S.wred[0][2] + S.wred[1][2] + bd2c[2];
            float d6 = S.wred[0][3] + S.wred[1][3] + bd2c[3];
            S.misc[3] = sigmoidf_(d0);
            S.misc[4] = sigmoidf_(d1);
            S.misc[5] = sigmoidf_(d2);
            float r1 = sigmoidf_(d6) * 0.98f + 0.01f;
            float a2 = r1 * r1; a2 = a2 * a2;
            S.misc[6] = r1; S.misc[7] = a2;
            S.misc[8] = __expf(0.1f * __logf(fmaxf(a2, 1e-6f)));  // a2^0.1
        }
        __syncthreads();

        basej = fmaf(S.misc[6], wb1s[63 * 128 + t], basej);  // ea1 row 63
        S.base[t] = basej;
        __syncthreads();

        // ---- phase 3: rays (8 lanes per ray, 16 rays) ----
        {
            const int g = t >> 3, l = t & 7;
            float u1 = uu[(n * MRAY + g) * 2 + 0];
            float u2 = uu[(n * MRAY + g) * 2 + 1];
            float a2 = S.misc[7];
            float ct = sqrtf((1.0f - u1) / (1.0f + (a2 - 1.0f) * u1));
            float st = sqrtf(fmaxf(1.0f - ct * ct, 0.0f));
            float phi = 6.28318530717958647692f * u2;
            float hl0 = st * __cosf(phi), hl1 = st * __sinf(phi), hl2 = ct;
            float H0 = S.bas[0] * hl0 + S.bas[1] * hl1 + S.bas[2] * hl2;
            float H1 = S.bas[3] * hl0 + S.bas[4] * hl1 + S.bas[5] * hl2;
            float H2 = S.bas[6] * hl0 + S.bas[7] * hl1 + S.bas[8] * hl2;
            float Vx = S.misc[0], Vy = S.misc[1], Vz = S.misc[2];
            float dvh = Vx * H0 + Vy * H1 + Vz * H2;
            float Lx = 2.0f * dvh * H0 - Vx;
            float Ly = 2.0f * dvh * H1 - Vy;
            float Lz = 2.0f * dvh * H2 - Vz;
            float linv = 1.0f / (sqrtf(Lx * Lx + Ly * Ly + Lz * Lz) + 1e-8f);
            Lx *= linv; Ly *= linv; Lz *= linv;
            float rv[9];
            rv[0] = Lx; rv[1] = Ly; rv[2] = Lz;
            rv[3] = S.bas[0] * H0 + S.bas[3] * H1 + S.bas[6] * H2;   // halfvec = basis^T H
            rv[4] = S.bas[1] * H0 + S.bas[4] * H1 + S.bas[7] * H2;
            rv[5] = S.bas[2] * H0 + S.bas[5] * H1 + S.bas[8] * H2;
            rv[6] = S.bas[0] * Lx + S.bas[3] * Ly + S.bas[6] * Lz;   // diffvec = basis^T L
            rv[7] = S.bas[1] * Lx + S.bas[4] * Ly + S.bas[7] * Lz;
            rv[8] = S.bas[2] * Lx + S.bas[5] * Ly + S.bas[8] * Lz;
            const int rows[9] = {3, 4, 5, 9, 10, 11, 12, 13, 14};

            float a0 = 0.f, a1 = 0.f, a2s = 0.f;
            #pragma unroll 4
            for (int i = 0; i < 16; i++) {
                int j = l + (i << 3);
                float hb = S.base[j];
                #pragma unroll
                for (int k = 0; k < 9; k++) hb = fmaf(rv[k], wb1s[rows[k] * 128 + j], hb);
                hb = fmaxf(hb, 0.0f);
                a0 = fmaf(hb, wb2s[j * 3 + 0], a0);
                a1 = fmaf(hb, wb2s[j * 3 + 1], a1);
                a2s = fmaf(hb, wb2s[j * 3 + 2], a2s);
            }
            a0 += __shfl_xor(a0, 1); a0 += __shfl_xor(a0, 2); a0 += __shfl_xor(a0, 4);
            a1 += __shfl_xor(a1, 1); a1 += __shfl_xor(a1, 2); a1 += __shfl_xor(a1, 4);
            a2s += __shfl_xor(a2s, 1); a2s += __shfl_xor(a2s, 2); a2s += __shfl_xor(a2s, 4);

            if (l == 0) {
                float b0 = sigmoidf_(a0 + bb2s[0]);
                float b1 = sigmoidf_(a1 + bb2s[1]);
                float b2 = sigmoidf_(a2s + bb2s[2]);
                int idx = n * MRAY + g;
                bool mk;
                if (flag == 0)      mk = ((const unsigned char*)raym)[idx] != 0;
                else if (flag == 2) mk = ((const unsigned long long*)raym)[idx] != 0ull;
                else                mk = ((const unsigned int*)raym)[idx] != 0u;
                float mf = mk ? 1.0f : 0.0f;
                float sc = S.misc[8];
                float lzp = fmaxf(Lz, 0.0f);
                S.rayacc[g][0] = (lzp * 1.0f + 0.1f) * sc * b0 * mf;
                S.rayacc[g][1] = (lzp * 0.9f + 0.1f) * sc * b1 * mf;
                S.rayacc[g][2] = (lzp * 0.8f + 0.1f) * sc * b2 * mf;
                S.rayacc[g][3] = mf;
            }
        }
        __syncthreads();

        // ---- phase 4: combine rays + diffuse, write out ----
        if (t < 3) {
            float s = 0.f, cnt = 0.f;
            #pragma unroll
            for (int g = 0; g < 16; g++) { s += S.rayacc[g][t]; cnt += S.rayacc[g][3]; }
            out[n * 3 + t] = s / (cnt + 1e-8f) + S.misc[3 + t];
        }
    }
}

extern "C" void kernel_launch(void* const* d_in, const int* in_sizes, int n_in,
                              void* d_out, int out_size, void* d_ws, size_t ws_size,
                              hipStream_t stream) {
    const float* xyzs    = (const float*)d_in[0];
    const float* app     = (const float*)d_in[1];
    const float* vdirs   = (const float*)d_in[2];
    const float* normals = (const float*)d_in[3];
    const float* noise   = (const float*)d_in[4];
    const float* uu      = (const float*)d_in[5];
    const float* Wd1     = (const float*)d_in[6];
    const float* bd1     = (const float*)d_in[7];
    const float* Wd2     = (const float*)d_in[8];
    const float* bd2     = (const float*)d_in[9];
    const float* Wb1     = (const float*)d_in[10];
    const float* bb1     = (const float*)d_in[11];
    const float* Wb2     = (const float*)d_in[12];
    const float* bb2     = (const float*)d_in[13];
    const void*  raym    = d_in[15];   // ray_mask; bounce_mask (d_in[14]) is implied by ray_mask
    int* flag = (int*)d_ws;
    float* out = (float*)d_out;

    detect_mask<<<1, 1, 0, stream>>>((const unsigned int*)raym, flag);
    rb_main<<<GRID, BLOCK, 0, stream>>>(xyzs, app, vdirs, normals, noise, uu,
                                        Wd1, bd1, Wd2, bd2, Wb1, bb1, Wb2, bb2,
                                        raym, flag, out);
}

// Round 2
// 143.875 us; speedup vs baseline: 2.7077x; 2.7077x over previous
//
#include <hip/hip_runtime.h>
#include <hip/hip_bf16.h>
#include <math.h>

#define NPTS 65536
#define MRAY 16
#define BLOCK 512
#define PPW 4
#define PPB 32
#define GRID 2048

__device__ __forceinline__ float sigmoidf_(float x){ return 1.0f/(1.0f+__expf(-x)); }
__device__ __forceinline__ float wsum64(float x){
  x += __shfl_xor(x,1); x += __shfl_xor(x,2); x += __shfl_xor(x,4);
  x += __shfl_xor(x,8); x += __shfl_xor(x,16); x += __shfl_xor(x,32);
  return x;
}
__device__ __forceinline__ float sel4(float a, float b, float c, float d, int p){
  float lo = (p&1) ? b : a;
  float hi = (p&1) ? d : c;
  return (p&2) ? hi : lo;
}

// Classify ray_mask element dtype from the raw words.
// flag: 0 = 1-byte (uint8 bool), 1 = 4-byte word (int32/float32; !=0 decode), 2 = 8-byte (int64)
__global__ void detect_mask(const unsigned int* __restrict__ rm, int* __restrict__ flag) {
    bool bad = false, isf32 = false, odd_nz = false, even_one = false;
    for (int i = 0; i < 512; i++) {
        unsigned v = rm[i];
        if (v != 0u && v != 1u && v != 0x3F800000u) bad = true;
        if (v == 0x3F800000u) isf32 = true;
        if ((i & 1) && v != 0u) odd_nz = true;
        if (!(i & 1) && v != 0u) even_one = true;
    }
    int f;
    if (bad) f = 0;
    else if (isf32) f = 1;
    else if (!odd_nz && even_one) f = 2;
    else f = 1;
    flag[0] = f;
}

// LDS: wbase[55][128] = Wb1 rows {0,1,2, 6,7,8, 15..62, 63}  (const part of bounce layer1)
//      wray[128][12]  = per-col j: Wb1 rows {3,4,5, 9..14}[.,j] + Wb2[j][0..2]
//      baseu[32][129] = per-point base vector (first 192 floats of each wave slice double as nf staging)
__global__ __launch_bounds__(BLOCK) void rb_main(
    const float* __restrict__ xyzs, const float* __restrict__ app,
    const float* __restrict__ vdirs, const float* __restrict__ normals,
    const float* __restrict__ noise, const float* __restrict__ uu,
    const float* __restrict__ Wd1, const float* __restrict__ bd1,
    const float* __restrict__ Wd2, const float* __restrict__ bd2,
    const float* __restrict__ Wb1, const float* __restrict__ bb1,
    const float* __restrict__ Wb2, const float* __restrict__ bb2,
    const void* __restrict__ raym, const int* __restrict__ flagp,
    float* __restrict__ out)
{
    __shared__ float wbase_s[55*128];
    __shared__ float wray_s[128*12];
    __shared__ float baseu[32*129];

    const int tid = threadIdx.x;
    for (int i = tid; i < 55*128; i += BLOCK){
        int s = i >> 7, c = i & 127;
        int row = s < 3 ? s : (s < 6 ? s + 3 : (s < 54 ? s + 9 : 63));
        wbase_s[i] = Wb1[row*128 + c];
    }
    for (int i = tid; i < 128*12; i += BLOCK){
        int j = i / 12, q = i - 12*j;
        float v;
        if (q < 9){ int row = q < 3 ? 3 + q : 6 + q; v = Wb1[row*128 + j]; }
        else       v = Wb2[j*3 + (q - 9)];
        wray_s[i] = v;
    }
    __syncthreads();  // only block-wide barrier; everything after is wave-local

    const int lane  = tid & 63;
    const int wid   = __builtin_amdgcn_readfirstlane(tid >> 6);
    const int pbase = blockIdx.x * PPB + wid * PPW;
    float* nfw = &baseu[wid * (PPW*129)];   // nf staging (overwritten later by base writes)

    // ---- phase 1: basis (lanes 0..3) + noise-features ----
    float bs[9];
    #pragma unroll
    for (int i = 0; i < 9; i++) bs[i] = 0.f;
    if (lane < PPW){
        int n = pbase + lane;
        float nx = normals[n*3+0], ny = normals[n*3+1], nz = normals[n*3+2];
        float inv = 1.0f/(sqrtf(nx*nx+ny*ny+nz*nz)+1e-8f);
        float bx = nx*inv, by = ny*inv, bz = nz*inv;
        float ux, uy, uz;
        if (fabsf(bz) < 0.99f){ ux=0.f; uy=0.f; uz=1.f; } else { ux=1.f; uy=0.f; uz=0.f; }
        float tx = uy*bz-uz*by, ty = uz*bx-ux*bz, tz = ux*by-uy*bx;
        float tin = 1.0f/(sqrtf(tx*tx+ty*ty+tz*tz)+1e-8f);
        tx*=tin; ty*=tin; tz*=tin;
        float ex = by*tz-bz*ty, ey = bz*tx-bx*tz, ez = bx*ty-by*tx;
        bs[0]=tx; bs[1]=ex; bs[2]=bx; bs[3]=ty; bs[4]=ey; bs[5]=by; bs[6]=tz; bs[7]=ez; bs[8]=bz;
    }
    #pragma unroll
    for (int c = 0; c < 3; c++){
        int idx = lane + 64*c;   // = p*48 + k, contiguous & coalesced
        nfw[idx] = fmaf(0.01f, noise[pbase*48 + idx], app[pbase*48 + idx]);
    }

    // ---- phase 2: dense layer1 + bounce const part (lane = hidden unit, 4 pts batched) ----
    float h[PPW][2], b[PPW][2];
    {
        float h0 = bd1[lane], h1 = bd1[lane+64];
        float b0 = bb1[lane], b1 = bb1[lane+64];
        #pragma unroll
        for (int p = 0; p < PPW; p++){ h[p][0]=h0; h[p][1]=h1; b[p][0]=b0; b[p][1]=b1; }
    }
    float vd[PPW][3];
    #pragma unroll
    for (int k = 0; k < 3; k++){
        float w0 = Wd1[k*128+lane], w1 = Wd1[k*128+64+lane];
        #pragma unroll
        for (int p = 0; p < PPW; p++){
            float s = xyzs[(pbase+p)*3+k];
            h[p][0]=fmaf(s,w0,h[p][0]); h[p][1]=fmaf(s,w1,h[p][1]);
        }
    }
    #pragma unroll
    for (int k = 0; k < 3; k++){
        float w0 = Wd1[(3+k)*128+lane], w1 = Wd1[(3+k)*128+64+lane];
        #pragma unroll
        for (int p = 0; p < PPW; p++){
            float s = vdirs[(pbase+p)*3+k]; vd[p][k] = s;
            h[p][0]=fmaf(s,w0,h[p][0]); h[p][1]=fmaf(s,w1,h[p][1]);
        }
    }
    #pragma unroll 8
    for (int k = 0; k < 48; k++){
        float w0 = Wd1[(6+k)*128+lane], w1 = Wd1[(6+k)*128+64+lane];
        #pragma unroll
        for (int p = 0; p < PPW; p++){
            float s = app[(pbase+p)*48+k];
            h[p][0]=fmaf(s,w0,h[p][0]); h[p][1]=fmaf(s,w1,h[p][1]);
        }
    }
    // bounce const: eV rows (slots 0..2)
    #pragma unroll
    for (int s = 0; s < 3; s++){
        float w0 = wbase_s[s*128+lane], w1 = wbase_s[s*128+64+lane];
        #pragma unroll
        for (int p = 0; p < PPW; p++){
            b[p][0]=fmaf(-vd[p][s],w0,b[p][0]); b[p][1]=fmaf(-vd[p][s],w1,b[p][1]);
        }
    }
    // eN rows (slots 3..5)
    #pragma unroll
    for (int s = 0; s < 3; s++){
        float w0 = wbase_s[(3+s)*128+lane], w1 = wbase_s[(3+s)*128+64+lane];
        #pragma unroll
        for (int p = 0; p < PPW; p++){
            float bn = __shfl(bs[3*s+2], p);
            b[p][0]=fmaf(bn,w0,b[p][0]); b[p][1]=fmaf(bn,w1,b[p][1]);
        }
    }
    // feat rows (slots 6..53), nf from LDS broadcast
    #pragma unroll 4
    for (int k = 0; k < 48; k++){
        float w0 = wbase_s[(6+k)*128+lane], w1 = wbase_s[(6+k)*128+64+lane];
        #pragma unroll
        for (int p = 0; p < PPW; p++){
            float nfv = nfw[p*48+k];
            b[p][0]=fmaf(nfv,w0,b[p][0]); b[p][1]=fmaf(nfv,w1,b[p][1]);
        }
    }

    // dense layer2 (cols 0,1,2,6) + per-point scalars
    float wd2v[2][4];
    #pragma unroll
    for (int r = 0; r < 2; r++){
        int j = lane + 64*r;
        wd2v[r][0]=Wd2[j*9+0]; wd2v[r][1]=Wd2[j*9+1]; wd2v[r][2]=Wd2[j*9+2]; wd2v[r][3]=Wd2[j*9+6];
    }
    const float sbd2_0=bd2[0], sbd2_1=bd2[1], sbd2_2=bd2[2], sbd2_6=bd2[6];
    float dif[PPW][3], r1v[PPW], a2v[PPW], sclv[PPW];
    #pragma unroll
    for (int p = 0; p < PPW; p++){
        float hr0 = fmaxf(h[p][0],0.f), hr1 = fmaxf(h[p][1],0.f);
        float d0 = wsum64(fmaf(hr0,wd2v[0][0], hr1*wd2v[1][0])) + sbd2_0;
        float d1 = wsum64(fmaf(hr0,wd2v[0][1], hr1*wd2v[1][1])) + sbd2_1;
        float d2 = wsum64(fmaf(hr0,wd2v[0][2], hr1*wd2v[1][2])) + sbd2_2;
        float d6 = wsum64(fmaf(hr0,wd2v[0][3], hr1*wd2v[1][3])) + sbd2_6;
        dif[p][0]=sigmoidf_(d0); dif[p][1]=sigmoidf_(d1); dif[p][2]=sigmoidf_(d2);
        float r1 = sigmoidf_(d6)*0.98f + 0.01f;
        float a2 = r1*r1; a2 = a2*a2;
        r1v[p]=r1; a2v[p]=a2;
        sclv[p]=__expf(0.1f*__logf(fmaxf(a2,1e-6f)));
    }
    // ea1 row (slot 54), then publish base (clobbers nf region -- all nf reads already done)
    {
        float w0 = wbase_s[54*128+lane], w1 = wbase_s[54*128+64+lane];
        #pragma unroll
        for (int p = 0; p < PPW; p++){
            float b0 = fmaf(r1v[p],w0,b[p][0]);
            float b1 = fmaf(r1v[p],w1,b[p][1]);
            baseu[(wid*PPW+p)*129 + lane]      = b0;
            baseu[(wid*PPW+p)*129 + 64 + lane] = b1;
        }
    }

    // ---- phase 3: rays (lane = pt*16 + ray) ----
    const int p4 = lane >> 4;
    const int m  = lane & 15;
    const int n  = pbase + p4;
    float bas[9];
    #pragma unroll
    for (int i = 0; i < 9; i++) bas[i] = __shfl(bs[i], p4);
    float a2s = sel4(a2v[0],a2v[1],a2v[2],a2v[3],p4);
    float scl = sel4(sclv[0],sclv[1],sclv[2],sclv[3],p4);
    float Vx = -sel4(vd[0][0],vd[1][0],vd[2][0],vd[3][0],p4);
    float Vy = -sel4(vd[0][1],vd[1][1],vd[2][1],vd[3][1],p4);
    float Vz = -sel4(vd[0][2],vd[1][2],vd[2][2],vd[3][2],p4);

    float u1 = uu[(n*MRAY+m)*2+0];
    float u2 = uu[(n*MRAY+m)*2+1];
    float ct = sqrtf((1.0f-u1)/(1.0f+(a2s-1.0f)*u1));
    float st = sqrtf(fmaxf(1.0f-ct*ct,0.0f));
    float phi = 6.28318530717958647692f*u2;
    float hl0 = st*__cosf(phi), hl1 = st*__sinf(phi), hl2 = ct;
    float H0 = bas[0]*hl0+bas[1]*hl1+bas[2]*hl2;
    float H1 = bas[3]*hl0+bas[4]*hl1+bas[5]*hl2;
    float H2 = bas[6]*hl0+bas[7]*hl1+bas[8]*hl2;
    float dvh = Vx*H0+Vy*H1+Vz*H2;
    float Lx = 2.f*dvh*H0-Vx, Ly = 2.f*dvh*H1-Vy, Lz = 2.f*dvh*H2-Vz;
    float linv = 1.0f/(sqrtf(Lx*Lx+Ly*Ly+Lz*Lz)+1e-8f);
    Lx*=linv; Ly*=linv; Lz*=linv;
    float rv0=Lx, rv1=Ly, rv2=Lz;
    float rv3 = bas[0]*H0+bas[3]*H1+bas[6]*H2;
    float rv4 = bas[1]*H0+bas[4]*H1+bas[7]*H2;
    float rv5 = bas[2]*H0+bas[5]*H1+bas[8]*H2;
    float rv6 = bas[0]*Lx+bas[3]*Ly+bas[6]*Lz;
    float rv7 = bas[1]*Lx+bas[4]*Ly+bas[7]*Lz;
    float rv8 = bas[2]*Lx+bas[5]*Ly+bas[8]*Lz;

    const float* bb = &baseu[(wid*PPW+p4)*129];
    float acc0=0.f, acc1=0.f, acc2=0.f;
    #pragma unroll 4
    for (int j = 0; j < 128; j++){
        const float4 wa  = *(const float4*)&wray_s[j*12];
        const float4 wbv = *(const float4*)&wray_s[j*12+4];
        const float4 wc  = *(const float4*)&wray_s[j*12+8];
        float hb = bb[j];
        hb = fmaf(rv0,wa.x,hb);  hb = fmaf(rv1,wa.y,hb);  hb = fmaf(rv2,wa.z,hb);
        hb = fmaf(rv3,wa.w,hb);  hb = fmaf(rv4,wbv.x,hb); hb = fmaf(rv5,wbv.y,hb);
        hb = fmaf(rv6,wbv.z,hb); hb = fmaf(rv7,wbv.w,hb); hb = fmaf(rv8,wc.x,hb);
        hb = fmaxf(hb,0.f);
        acc0 = fmaf(hb,wc.y,acc0); acc1 = fmaf(hb,wc.z,acc1); acc2 = fmaf(hb,wc.w,acc2);
    }

    const float sbb2_0=bb2[0], sbb2_1=bb2[1], sbb2_2=bb2[2];
    float e0 = sigmoidf_(acc0+sbb2_0), e1 = sigmoidf_(acc1+sbb2_1), e2 = sigmoidf_(acc2+sbb2_2);
    int midx = n*MRAY + m;
    const int flag = flagp[0];
    bool mk;
    if (flag == 0)      mk = ((const unsigned char*)raym)[midx] != 0;
    else if (flag == 2) mk = ((const unsigned long long*)raym)[midx] != 0ull;
    else                mk = ((const unsigned int*)raym)[midx] != 0u;
    float mf = mk ? 1.f : 0.f;
    float lzp = fmaxf(rv2, 0.f);
    float c0 = (lzp*1.0f+0.1f)*scl*e0*mf;
    float c1 = (lzp*0.9f+0.1f)*scl*e1*mf;
    float c2 = (lzp*0.8f+0.1f)*scl*e2*mf;
    #pragma unroll
    for (int off = 1; off < 16; off <<= 1){
        c0 += __shfl_xor(c0,off); c1 += __shfl_xor(c1,off);
        c2 += __shfl_xor(c2,off); mf += __shfl_xor(mf,off);
    }
    if (m == 0){
        float den = mf + 1e-8f;
        float d0 = sel4(dif[0][0],dif[1][0],dif[2][0],dif[3][0],p4);
        float d1 = sel4(dif[0][1],dif[1][1],dif[2][1],dif[3][1],p4);
        float d2 = sel4(dif[0][2],dif[1][2],dif[2][2],dif[3][2],p4);
        out[n*3+0] = c0/den + d0;
        out[n*3+1] = c1/den + d1;
        out[n*3+2] = c2/den + d2;
    }
}

extern "C" void kernel_launch(void* const* d_in, const int* in_sizes, int n_in,
                              void* d_out, int out_size, void* d_ws, size_t ws_size,
                              hipStream_t stream) {
    const float* xyzs    = (const float*)d_in[0];
    const float* app     = (const float*)d_in[1];
    const float* vdirs   = (const float*)d_in[2];
    const float* normals = (const float*)d_in[3];
    const float* noise   = (const float*)d_in[4];
    const float* uu      = (const float*)d_in[5];
    const float* Wd1     = (const float*)d_in[6];
    const float* bd1     = (const float*)d_in[7];
    const float* Wd2     = (const float*)d_in[8];
    const float* bd2     = (const float*)d_in[9];
    const float* Wb1     = (const float*)d_in[10];
    const float* bb1     = (const float*)d_in[11];
    const float* Wb2     = (const float*)d_in[12];
    const float* bb2     = (const float*)d_in[13];
    const void*  raym    = d_in[15];
    int* flag = (int*)d_ws;
    float* out = (float*)d_out;

    detect_mask<<<1, 1, 0, stream>>>((const unsigned int*)raym, flag);
    rb_main<<<GRID, BLOCK, 0, stream>>>(xyzs, app, vdirs, normals, noise, uu,
                                        Wd1, bd1, Wd2, bd2, Wb1, bb1, Wb2, bb2,
                                        raym, flag, out);
}